// Round 9
// baseline (245.467 us; speedup 1.0000x reference)
//
#include <hip/hip_runtime.h>
#include <stdint.h>

#define HEADS 16
#define HD    64
#define SEQ   2048
#define BATCH 2
#define EMB   1024

using short8  = __attribute__((ext_vector_type(8))) short;
using float4v = __attribute__((ext_vector_type(4))) float;
using f32x16  = __attribute__((ext_vector_type(16))) float;

// round-half-up f32 -> bf16 (2 VALU ops); inputs never NaN/overflow here
__device__ __forceinline__ unsigned int f2bfr(float f) {
    return (__float_as_uint(f) + 0x8000u) >> 16;
}

// pack two f32 -> bf16x2 dword (RNE), single VOP3
__device__ __forceinline__ unsigned int cvt_pk_bf16(float lo, float hi) {
    unsigned int r;
    asm("v_cvt_pk_bf16_f32 %0, %1, %2" : "=v"(r) : "v"(lo), "v"(hi));
    return r;
}

__device__ __forceinline__ short8 mk8(unsigned int a, unsigned int b,
                                      unsigned int c, unsigned int d) {
    union { unsigned int u[4]; short8 s; } x;
    x.u[0] = a; x.u[1] = b; x.u[2] = c; x.u[3] = d;
    return x.s;
}

// ---------------- Wo fp32 -> bf16 ----------------
__global__ __launch_bounds__(256) void cvt_wo_kernel(const float* __restrict__ Wo,
                                                     unsigned short* __restrict__ Wob) {
    int i = (blockIdx.x * 256 + threadIdx.x) * 4;
    float4 v = *(const float4*)(Wo + i);
    uint2 o;
    o.x = f2bfr(v.x) | (f2bfr(v.y) << 16);
    o.y = f2bfr(v.z) | (f2bfr(v.w) << 16);
    *(uint2*)(Wob + i) = o;
}

// ---------------- QKV projection (MFMA) ----------------
// (Round-4 proven version)
// z=0: queries->Qp (B,H,S,D) [pre-scaled by 0.125*log2e via Wq]
// z=1: keys->Kp (B,H,S,D)    z=2: values->Vt (B,H,D,S)
__global__ __launch_bounds__(256) void proj_kernel(
    const float* __restrict__ Vx, const float* __restrict__ Kx, const float* __restrict__ Qx,
    const float* __restrict__ Wv, const float* __restrict__ Wk, const float* __restrict__ Wq,
    unsigned short* __restrict__ Qp, unsigned short* __restrict__ Kp,
    unsigned short* __restrict__ Vt) {
    __shared__ __align__(16) unsigned short Ws[64 * 72];   // B-frag: Ws[e][d]
    __shared__ __align__(16) unsigned short xs[64 * 72];   // A-frag: xs[s][d]; reused for repack
    __shared__ __align__(16) unsigned short vt2[64 * 72];  // z==2 transpose buffer [e][s]

    const int t = threadIdx.x, w = t >> 6, lane = t & 63, cl = lane & 15, quad = lane >> 4;
    const int z  = blockIdx.z;
    const int bh = blockIdx.y;
    const int b  = bh >> 4, h = bh & 15;
    const int s0 = blockIdx.x * 64;

    const float* x = (z == 0) ? Qx : (z == 1) ? Kx : Vx;
    const float* W = (z == 0) ? Wq : (z == 1) ? Wk : Wv;
    const float scale = (z == 0) ? 0.18033688011112044f : 1.0f;  // 0.125*log2(e)

#pragma unroll
    for (int rep = 0; rep < 4; ++rep) {
        int idx = rep * 1024 + t * 4;
        int e = idx >> 6, d0 = idx & 63;
        float4 w4 = *(const float4*)(W + idx);
        uint2 pk;
        pk.x = f2bfr(w4.x * scale) | (f2bfr(w4.y * scale) << 16);
        pk.y = f2bfr(w4.z * scale) | (f2bfr(w4.w * scale) << 16);
        *(uint2*)(&Ws[e * 72 + d0]) = pk;

        int s = e;
        float4 v4 = *(const float4*)(x + (size_t)(b * SEQ + s0 + s) * EMB + h * 64 + d0);
        uint2 px;
        px.x = f2bfr(v4.x) | (f2bfr(v4.y) << 16);
        px.y = f2bfr(v4.z) | (f2bfr(v4.w) << 16);
        *(uint2*)(&xs[s * 72 + d0]) = px;
    }
    __syncthreads();

    short8 a0 = *(const short8*)(&xs[(w * 16 + cl) * 72 + quad * 8]);
    short8 a1 = *(const short8*)(&xs[(w * 16 + cl) * 72 + 32 + quad * 8]);
    float4v c[4];
#pragma unroll
    for (int nt = 0; nt < 4; ++nt) c[nt] = (float4v){0.f, 0.f, 0.f, 0.f};
#pragma unroll
    for (int nt = 0; nt < 4; ++nt) {
        short8 b0 = *(const short8*)(&Ws[(nt * 16 + cl) * 72 + quad * 8]);
        c[nt] = __builtin_amdgcn_mfma_f32_16x16x32_bf16(a0, b0, c[nt], 0, 0, 0);
        short8 b1 = *(const short8*)(&Ws[(nt * 16 + cl) * 72 + 32 + quad * 8]);
        c[nt] = __builtin_amdgcn_mfma_f32_16x16x32_bf16(a1, b1, c[nt], 0, 0, 0);
    }

    if (z < 2) {
#pragma unroll
        for (int nt = 0; nt < 4; ++nt)
#pragma unroll
            for (int r = 0; r < 4; ++r)
                xs[(w * 16 + quad * 4 + r) * 72 + nt * 16 + cl] =
                    (unsigned short)f2bfr(c[nt][r]);
        unsigned short* outp = (z == 0) ? Qp : Kp;
        int sl = w * 16 + (lane >> 2), c0 = (lane & 3) * 16;
        uint4 o0 = *(const uint4*)(&xs[sl * 72 + c0]);
        uint4 o1 = *(const uint4*)(&xs[sl * 72 + c0 + 8]);
        size_t base = ((size_t)bh * SEQ + s0 + sl) * 64 + c0;
        *(uint4*)(outp + base)     = o0;
        *(uint4*)(outp + base + 8) = o1;
    } else {
#pragma unroll
        for (int nt = 0; nt < 4; ++nt)
#pragma unroll
            for (int r = 0; r < 4; ++r)
                vt2[(nt * 16 + cl) * 72 + w * 16 + quad * 4 + r] =
                    (unsigned short)f2bfr(c[nt][r]);
        __syncthreads();
        int e = t >> 2, sc0 = (t & 3) * 16;
        uint4 o0 = *(const uint4*)(&vt2[e * 72 + sc0]);
        uint4 o1 = *(const uint4*)(&vt2[e * 72 + sc0 + 8]);
        size_t base = ((size_t)bh * 64 + e) * SEQ + s0 + sc0;
        *(uint4*)(Vt + base)     = o0;
        *(uint4*)(Vt + base + 8) = o1;
    }
}

// ---------------- flash attention, swapped-QK 32x32 in-register softmax ----------------
// (verbatim Round-4 kernel: proven correct at 88.5us. KVBLK=128 abandoned after
// two unexplained correctness failures (R3, R8) on timing-shifted variants.)
__global__ __launch_bounds__(256) void attn_kernel(
    const unsigned short* __restrict__ Qp, const unsigned short* __restrict__ Kp,
    const unsigned short* __restrict__ Vt, unsigned short* __restrict__ AO) {
    __shared__ __align__(16) unsigned short Ks[2][64 * 72];   // [key][d]
    __shared__ __align__(16) unsigned short Vs[2][64 * 72];   // [d][key]

    const int t = threadIdx.x;
    const int w = t >> 6, lane = t & 63;
    const int l31 = lane & 31, h = lane >> 5;

    // XCD-aware swizzle: lid%8 -> XCD; give each XCD 4 heads (K+V = 2MB fits L2)
    const int lid = blockIdx.x;
    const int bh  = ((lid & 7) << 2) | ((lid >> 3) & 3);
    const int q0  = (lid >> 5) * 128;

    const size_t hbase = (size_t)bh * SEQ * 64;
    const unsigned short* Kbase = Kp + hbase;
    const unsigned short* Vbase = Vt + hbase;

    // Q B-frags: lane holds q = q0 + w*32 + l31, d = dt*16 + h*8 + j
    short8 qf[4];
    {
        const unsigned short* qr = Qp + hbase + (size_t)(q0 + w * 32 + l31) * 64 + h * 8;
#pragma unroll
        for (int dt = 0; dt < 4; ++dt) qf[dt] = *(const short8*)(qr + dt * 16);
    }

    short8 ones;
#pragma unroll
    for (int i = 0; i < 8; ++i) ones[i] = (short)0x3F80;  // bf16 1.0

    f32x16 o0, o1, ls;
#pragma unroll
    for (int r = 0; r < 16; ++r) { o0[r] = 0.f; o1[r] = 0.f; ls[r] = 0.f; }

    const int srow = t >> 3;       // 0..31
    const int scol = (t & 7) * 8;  // 0..56

    uint4 kreg[2], vreg[2];
#pragma unroll
    for (int p = 0; p < 2; ++p) {
        int row = srow + p * 32;
        kreg[p] = *(const uint4*)(Kbase + row * 64 + scol);
        vreg[p] = *(const uint4*)(Vbase + (size_t)row * SEQ + scol);
    }

    for (int kc = 0; kc < SEQ / 64; ++kc) {
        const int buf = kc & 1;
#pragma unroll
        for (int p = 0; p < 2; ++p) {
            int row = srow + p * 32;
            *(uint4*)(&Ks[buf][row * 72 + scol]) = kreg[p];
            *(uint4*)(&Vs[buf][row * 72 + scol]) = vreg[p];
        }
        __syncthreads();
        if (kc + 1 < SEQ / 64) {
#pragma unroll
            for (int p = 0; p < 2; ++p) {
                int row = srow + p * 32;
                kreg[p] = *(const uint4*)(Kbase + (size_t)(kc + 1) * 4096 + row * 64 + scol);
                vreg[p] = *(const uint4*)(Vbase + (size_t)row * SEQ + (kc + 1) * 64 + scol);
            }
        }

        // S^T tiles: C[key][q], key = ktile*32 + (reg&3)+8*(reg>>2)+4h, q = l31
        f32x16 s0, s1;
#pragma unroll
        for (int r = 0; r < 16; ++r) { s0[r] = 0.f; s1[r] = 0.f; }

        __builtin_amdgcn_s_setprio(1);
#pragma unroll
        for (int dt = 0; dt < 4; ++dt) {
            short8 k0 = *(const short8*)(&Ks[buf][l31 * 72 + dt * 16 + h * 8]);
            short8 k1 = *(const short8*)(&Ks[buf][(32 + l31) * 72 + dt * 16 + h * 8]);
            s0 = __builtin_amdgcn_mfma_f32_32x32x16_bf16(k0, qf[dt], s0, 0, 0, 0);
            s1 = __builtin_amdgcn_mfma_f32_32x32x16_bf16(k1, qf[dt], s1, 0, 0, 0);
        }
        __builtin_amdgcn_s_setprio(0);

#pragma unroll
        for (int r = 0; r < 16; ++r) {
            s0[r] = __builtin_amdgcn_exp2f(s0[r]);
            s1[r] = __builtin_amdgcn_exp2f(s1[r]);
        }

        // lane-local pack to PV A-frags; partner 4-groups via shfl_xor(32)
        short8 fr[4];
        {
            unsigned e0 = cvt_pk_bf16(s0[0],  s0[1]),  e1 = cvt_pk_bf16(s0[2],  s0[3]);
            unsigned e2 = cvt_pk_bf16(s0[4],  s0[5]),  e3 = cvt_pk_bf16(s0[6],  s0[7]);
            unsigned e4 = cvt_pk_bf16(s0[8],  s0[9]),  e5 = cvt_pk_bf16(s0[10], s0[11]);
            unsigned e6 = cvt_pk_bf16(s0[12], s0[13]), e7 = cvt_pk_bf16(s0[14], s0[15]);
            unsigned x0 = __shfl_xor(e0, 32), x1 = __shfl_xor(e1, 32);
            unsigned x2 = __shfl_xor(e2, 32), x3 = __shfl_xor(e3, 32);
            unsigned x4 = __shfl_xor(e4, 32), x5 = __shfl_xor(e5, 32);
            unsigned x6 = __shfl_xor(e6, 32), x7 = __shfl_xor(e7, 32);
            fr[0] = mk8(h ? x2 : e0, h ? x3 : e1, h ? e2 : x0, h ? e3 : x1);
            fr[1] = mk8(h ? x6 : e4, h ? x7 : e5, h ? e6 : x4, h ? e7 : x5);
        }
        {
            unsigned e0 = cvt_pk_bf16(s1[0],  s1[1]),  e1 = cvt_pk_bf16(s1[2],  s1[3]);
            unsigned e2 = cvt_pk_bf16(s1[4],  s1[5]),  e3 = cvt_pk_bf16(s1[6],  s1[7]);
            unsigned e4 = cvt_pk_bf16(s1[8],  s1[9]),  e5 = cvt_pk_bf16(s1[10], s1[11]);
            unsigned e6 = cvt_pk_bf16(s1[12], s1[13]), e7 = cvt_pk_bf16(s1[14], s1[15]);
            unsigned x0 = __shfl_xor(e0, 32), x1 = __shfl_xor(e1, 32);
            unsigned x2 = __shfl_xor(e2, 32), x3 = __shfl_xor(e3, 32);
            unsigned x4 = __shfl_xor(e4, 32), x5 = __shfl_xor(e5, 32);
            unsigned x6 = __shfl_xor(e6, 32), x7 = __shfl_xor(e7, 32);
            fr[2] = mk8(h ? x2 : e0, h ? x3 : e1, h ? e2 : x0, h ? e3 : x1);
            fr[3] = mk8(h ? x6 : e4, h ? x7 : e5, h ? e6 : x4, h ? e7 : x5);
        }

        // O += P*V ; l += P*ones (C rows align with O rows)
        __builtin_amdgcn_s_setprio(1);
#pragma unroll
        for (int c = 0; c < 4; ++c) {
            short8 bv0 = *(const short8*)(&Vs[buf][l31 * 72 + c * 16 + h * 8]);
            short8 bv1 = *(const short8*)(&Vs[buf][(32 + l31) * 72 + c * 16 + h * 8]);
            o0 = __builtin_amdgcn_mfma_f32_32x32x16_bf16(fr[c], bv0, o0, 0, 0, 0);
            o1 = __builtin_amdgcn_mfma_f32_32x32x16_bf16(fr[c], bv1, o1, 0, 0, 0);
            ls = __builtin_amdgcn_mfma_f32_32x32x16_bf16(fr[c], ones,  ls, 0, 0, 0);
        }
        __builtin_amdgcn_s_setprio(0);
    }

    float inv[16];
#pragma unroll
    for (int r = 0; r < 16; ++r) inv[r] = 1.0f / ls[r];
#pragma unroll
    for (int r = 0; r < 16; ++r) {
        int row = q0 + w * 32 + (r & 3) + 8 * (r >> 2) + 4 * h;
        size_t rb = hbase + (size_t)row * 64 + l31;
        AO[rb]      = (unsigned short)f2bfr(o0[r] * inv[r]);
        AO[rb + 32] = (unsigned short)f2bfr(o1[r] * inv[r]);
    }
}

// ---------------- output projection: out = AO @ Wob^T + bo ----------------
// R4's barrier-free per-wave GEMM, re-tiled 32x64 -> 32x32 per wave:
// 4096 waves = 4 waves/SIMD (was 2) for 2x latency hiding; zero LDS.
// Bijective XCD swizzle: 1024 blocks = 8 XCDs x 128 contiguous-mt chunks
// -> per-XCD working set = 1MB A-slice + 2MB Wob, fits 4MB L2.
// Per-lane fragment algebra identical to the proven R4 version.
__global__ __launch_bounds__(256) void outproj_kernel(
    const unsigned short* __restrict__ AO, const unsigned short* __restrict__ Wob,
    const float* __restrict__ bo, float* __restrict__ out) {
    const int t = threadIdx.x, w = t >> 6, lane = t & 63;
    const int l31 = lane & 31, h = lane >> 5;

    const int bid  = blockIdx.x;               // 1024 blocks
    const int sbid = (bid & 7) * 128 + (bid >> 3);
    const int wid  = sbid * 4 + w;             // 4096 waves
    const int mt   = wid >> 5;                 // 0..127 : 32-row tile of out
    const int et   = wid & 31;                 // 0..31  : 32-col tile of out
    const int m0   = mt * 32, e0 = et * 32;
    const int b    = m0 >> 11;                 // batch (2048 % 32 == 0, no crossing)
    const int s    = (m0 & 2047) + l31;        // seq row for this lane

    const unsigned short* pA = AO + ((size_t)(b * 16) * SEQ + s) * 64 + h * 8;
    const unsigned short* pB = Wob + (size_t)(e0 + l31) * EMB + h * 8;

    f32x16 c0;
#pragma unroll
    for (int r = 0; r < 16; ++r) c0[r] = 0.f;

    for (int hh = 0; hh < 16; ++hh) {
#pragma unroll
        for (int k4 = 0; k4 < 4; ++k4) {
            short8 a  = *(const short8*)(pA + k4 * 16);
            short8 bb = *(const short8*)(pB + hh * 64 + k4 * 16);
            c0 = __builtin_amdgcn_mfma_f32_32x32x16_bf16(a, bb, c0, 0, 0, 0);
        }
        pA += (size_t)SEQ * 64;  // next head along k
    }

    const float bias0 = bo[e0 + l31];
#pragma unroll
    for (int r = 0; r < 16; ++r) {
        int m = m0 + (r & 3) + 8 * (r >> 2) + 4 * h;
        out[(size_t)m * EMB + e0 + l31] = c0[r] + bias0;
    }
}

extern "C" void kernel_launch(void* const* d_in, const int* in_sizes, int n_in,
                              void* d_out, int out_size, void* d_ws, size_t ws_size,
                              hipStream_t stream) {
    const float* values  = (const float*)d_in[0];
    const float* keys    = (const float*)d_in[1];
    const float* queries = (const float*)d_in[2];
    const float* Wv = (const float*)d_in[3];
    const float* Wk = (const float*)d_in[4];
    const float* Wq = (const float*)d_in[5];
    const float* Wo = (const float*)d_in[6];
    const float* bo = (const float*)d_in[7];
    float* out = (float*)d_out;

    char* ws = (char*)d_ws;
    unsigned short* Qp  = (unsigned short*)(ws);                 // 8 MB (B,H,S,D) bf16
    unsigned short* Kp  = (unsigned short*)(ws + (8u  << 20));   // 8 MB (B,H,S,D) bf16
    unsigned short* Vt  = (unsigned short*)(ws + (16u << 20));   // 8 MB (B,H,D,S) bf16
    unsigned short* AO  = (unsigned short*)(ws + (24u << 20));   // 8 MB (B,H,S,D) bf16
    unsigned short* Wob = (unsigned short*)(ws + (32u << 20));   // 2 MB [e][k] bf16

    cvt_wo_kernel<<<dim3(1024), dim3(256), 0, stream>>>(Wo, Wob);
    proj_kernel<<<dim3(SEQ / 64, BATCH * HEADS, 3), dim3(256), 0, stream>>>(
        values, keys, queries, Wv, Wk, Wq, Qp, Kp, Vt);
    attn_kernel<<<dim3((SEQ / 128) * BATCH * HEADS), dim3(256), 0, stream>>>(Qp, Kp, Vt, AO);
    outproj_kernel<<<dim3(((EMB / 32) * ((BATCH * SEQ) / 32)) / 4), dim3(256), 0, stream>>>(
        AO, Wob, bo, out);
}

// Round 10
// 230.642 us; speedup vs baseline: 1.0643x; 1.0643x over previous
//
#include <hip/hip_runtime.h>
#include <stdint.h>

#define HEADS 16
#define HD    64
#define SEQ   2048
#define BATCH 2
#define EMB   1024

using short8  = __attribute__((ext_vector_type(8))) short;
using float4v = __attribute__((ext_vector_type(4))) float;
using f32x16  = __attribute__((ext_vector_type(16))) float;

// round-half-up f32 -> bf16 (2 VALU ops); inputs never NaN/overflow here
__device__ __forceinline__ unsigned int f2bfr(float f) {
    return (__float_as_uint(f) + 0x8000u) >> 16;
}

// pack two f32 -> bf16x2 dword (RNE), single VOP3
__device__ __forceinline__ unsigned int cvt_pk_bf16(float lo, float hi) {
    unsigned int r;
    asm("v_cvt_pk_bf16_f32 %0, %1, %2" : "=v"(r) : "v"(lo), "v"(hi));
    return r;
}

// swap with lane^1 (quad_perm [1,0,3,2])
__device__ __forceinline__ unsigned int dpp_xor1(unsigned int x) {
    return (unsigned int)__builtin_amdgcn_update_dpp(0, (int)x, 0xB1, 0xF, 0xF, true);
}

__device__ __forceinline__ short8 mk8(unsigned int a, unsigned int b,
                                      unsigned int c, unsigned int d) {
    union { unsigned int u[4]; short8 s; } x;
    x.u[0] = a; x.u[1] = b; x.u[2] = c; x.u[3] = d;
    return x.s;
}

// ---------------- QKV projection (MFMA) + fused Wo conversion ----------------
// z=0: queries->Qp (B,H,S,D) [pre-scaled by 0.125*log2e via Wq]
// z=1: keys->Kp (B,H,S,D)    z=2: values->Vt (B,H,D,S)
// z=3: Wo fp32 -> bf16 (folded former cvt_wo_kernel; saves one dispatch)
__global__ __launch_bounds__(256) void proj_kernel(
    const float* __restrict__ Vx, const float* __restrict__ Kx, const float* __restrict__ Qx,
    const float* __restrict__ Wv, const float* __restrict__ Wk, const float* __restrict__ Wq,
    const float* __restrict__ Wo,
    unsigned short* __restrict__ Qp, unsigned short* __restrict__ Kp,
    unsigned short* __restrict__ Vt, unsigned short* __restrict__ Wob) {
    __shared__ __align__(16) unsigned short Ws[64 * 72];   // B-frag: Ws[e][d]
    __shared__ __align__(16) unsigned short xs[64 * 72];   // A-frag: xs[s][d]; reused for repack
    __shared__ __align__(16) unsigned short vt2[64 * 72];  // z==2 transpose buffer [e][s]

    const int t = threadIdx.x, w = t >> 6, lane = t & 63, cl = lane & 15, quad = lane >> 4;
    const int z  = blockIdx.z;

    if (z == 3) {  // Wo fp32 -> bf16 (block-uniform branch, no barriers touched)
        int cb = blockIdx.y * 32 + blockIdx.x;
        int i = (cb * 256 + t) * 4;
        float4 v = *(const float4*)(Wo + i);
        uint2 o;
        o.x = f2bfr(v.x) | (f2bfr(v.y) << 16);
        o.y = f2bfr(v.z) | (f2bfr(v.w) << 16);
        *(uint2*)(Wob + i) = o;
        return;
    }

    const int bh = blockIdx.y;
    const int b  = bh >> 4, h = bh & 15;
    const int s0 = blockIdx.x * 64;

    const float* x = (z == 0) ? Qx : (z == 1) ? Kx : Vx;
    const float* W = (z == 0) ? Wq : (z == 1) ? Wk : Wv;
    const float scale = (z == 0) ? 0.18033688011112044f : 1.0f;  // 0.125*log2(e)

#pragma unroll
    for (int rep = 0; rep < 4; ++rep) {
        int idx = rep * 1024 + t * 4;
        int e = idx >> 6, d0 = idx & 63;
        float4 w4 = *(const float4*)(W + idx);
        uint2 pk;
        pk.x = f2bfr(w4.x * scale) | (f2bfr(w4.y * scale) << 16);
        pk.y = f2bfr(w4.z * scale) | (f2bfr(w4.w * scale) << 16);
        *(uint2*)(&Ws[e * 72 + d0]) = pk;

        int s = e;
        float4 v4 = *(const float4*)(x + (size_t)(b * SEQ + s0 + s) * EMB + h * 64 + d0);
        uint2 px;
        px.x = f2bfr(v4.x) | (f2bfr(v4.y) << 16);
        px.y = f2bfr(v4.z) | (f2bfr(v4.w) << 16);
        *(uint2*)(&xs[s * 72 + d0]) = px;
    }
    __syncthreads();

    short8 a0 = *(const short8*)(&xs[(w * 16 + cl) * 72 + quad * 8]);
    short8 a1 = *(const short8*)(&xs[(w * 16 + cl) * 72 + 32 + quad * 8]);
    float4v c[4];
#pragma unroll
    for (int nt = 0; nt < 4; ++nt) c[nt] = (float4v){0.f, 0.f, 0.f, 0.f};
#pragma unroll
    for (int nt = 0; nt < 4; ++nt) {
        short8 b0 = *(const short8*)(&Ws[(nt * 16 + cl) * 72 + quad * 8]);
        c[nt] = __builtin_amdgcn_mfma_f32_16x16x32_bf16(a0, b0, c[nt], 0, 0, 0);
        short8 b1 = *(const short8*)(&Ws[(nt * 16 + cl) * 72 + 32 + quad * 8]);
        c[nt] = __builtin_amdgcn_mfma_f32_16x16x32_bf16(a1, b1, c[nt], 0, 0, 0);
    }

    if (z < 2) {
        // repack via DPP pair-pack (cols cl,cl^1 in adjacent lanes): 8 ds_write_b32
        // replaces 16 ds_write_u16. Rounding identical (+0x8000 >> 16).
        const int even = ((lane & 1) == 0);
        const unsigned int psel = even ? 0x03020706u : 0x07060302u;
        const int evoff = even ? 0 : 16;  // odd lanes write nt{2,3} dword blocks
        unsigned int* Pw = (unsigned int*)xs;
#pragma unroll
        for (int r = 0; r < 4; ++r) {
            unsigned int rr[4], wd[4];
#pragma unroll
            for (int nt = 0; nt < 4; ++nt)
                rr[nt] = __float_as_uint(c[nt][r]) + 0x8000u;
#pragma unroll
            for (int nt = 0; nt < 4; ++nt) {
                unsigned int nb = dpp_xor1(rr[nt]);
                wd[nt] = __builtin_amdgcn_perm(rr[nt], nb, psel);
            }
            int dwbase = (w * 16 + quad * 4 + r) * 36 + evoff + (cl >> 1);
            Pw[dwbase]     = even ? wd[0] : wd[2];
            Pw[dwbase + 8] = even ? wd[1] : wd[3];
        }
        unsigned short* outp = (z == 0) ? Qp : Kp;
        int sl = w * 16 + (lane >> 2), c0 = (lane & 3) * 16;
        uint4 o0 = *(const uint4*)(&xs[sl * 72 + c0]);
        uint4 o1 = *(const uint4*)(&xs[sl * 72 + c0 + 8]);
        size_t base = ((size_t)bh * SEQ + s0 + sl) * 64 + c0;
        *(uint4*)(outp + base)     = o0;
        *(uint4*)(outp + base + 8) = o1;
    } else {
        // transpose repack: lane holds 4 consecutive cols (r) per nt-row ->
        // pack locally, 4 aligned uint2 writes replace 16 ds_write_u16.
#pragma unroll
        for (int nt = 0; nt < 4; ++nt) {
            uint2 pk;
            pk.x = f2bfr(c[nt][0]) | (f2bfr(c[nt][1]) << 16);
            pk.y = f2bfr(c[nt][2]) | (f2bfr(c[nt][3]) << 16);
            *(uint2*)(&vt2[(nt * 16 + cl) * 72 + w * 16 + quad * 4]) = pk;
        }
        __syncthreads();
        int e = t >> 2, sc0 = (t & 3) * 16;
        uint4 o0 = *(const uint4*)(&vt2[e * 72 + sc0]);
        uint4 o1 = *(const uint4*)(&vt2[e * 72 + sc0 + 8]);
        size_t base = ((size_t)bh * 64 + e) * SEQ + s0 + sc0;
        *(uint4*)(Vt + base)     = o0;
        *(uint4*)(Vt + base + 8) = o1;
    }
}

// ---------------- flash attention, swapped-QK 32x32 in-register softmax ----------------
// (verbatim Round-4 kernel: proven correct at 88.5us)
__global__ __launch_bounds__(256) void attn_kernel(
    const unsigned short* __restrict__ Qp, const unsigned short* __restrict__ Kp,
    const unsigned short* __restrict__ Vt, unsigned short* __restrict__ AO) {
    __shared__ __align__(16) unsigned short Ks[2][64 * 72];   // [key][d]
    __shared__ __align__(16) unsigned short Vs[2][64 * 72];   // [d][key]

    const int t = threadIdx.x;
    const int w = t >> 6, lane = t & 63;
    const int l31 = lane & 31, h = lane >> 5;

    // XCD-aware swizzle: lid%8 -> XCD; give each XCD 4 heads (K+V = 2MB fits L2)
    const int lid = blockIdx.x;
    const int bh  = ((lid & 7) << 2) | ((lid >> 3) & 3);
    const int q0  = (lid >> 5) * 128;

    const size_t hbase = (size_t)bh * SEQ * 64;
    const unsigned short* Kbase = Kp + hbase;
    const unsigned short* Vbase = Vt + hbase;

    // Q B-frags: lane holds q = q0 + w*32 + l31, d = dt*16 + h*8 + j
    short8 qf[4];
    {
        const unsigned short* qr = Qp + hbase + (size_t)(q0 + w * 32 + l31) * 64 + h * 8;
#pragma unroll
        for (int dt = 0; dt < 4; ++dt) qf[dt] = *(const short8*)(qr + dt * 16);
    }

    short8 ones;
#pragma unroll
    for (int i = 0; i < 8; ++i) ones[i] = (short)0x3F80;  // bf16 1.0

    f32x16 o0, o1, ls;
#pragma unroll
    for (int r = 0; r < 16; ++r) { o0[r] = 0.f; o1[r] = 0.f; ls[r] = 0.f; }

    const int srow = t >> 3;       // 0..31
    const int scol = (t & 7) * 8;  // 0..56

    uint4 kreg[2], vreg[2];
#pragma unroll
    for (int p = 0; p < 2; ++p) {
        int row = srow + p * 32;
        kreg[p] = *(const uint4*)(Kbase + row * 64 + scol);
        vreg[p] = *(const uint4*)(Vbase + (size_t)row * SEQ + scol);
    }

    for (int kc = 0; kc < SEQ / 64; ++kc) {
        const int buf = kc & 1;
#pragma unroll
        for (int p = 0; p < 2; ++p) {
            int row = srow + p * 32;
            *(uint4*)(&Ks[buf][row * 72 + scol]) = kreg[p];
            *(uint4*)(&Vs[buf][row * 72 + scol]) = vreg[p];
        }
        __syncthreads();
        if (kc + 1 < SEQ / 64) {
#pragma unroll
            for (int p = 0; p < 2; ++p) {
                int row = srow + p * 32;
                kreg[p] = *(const uint4*)(Kbase + (size_t)(kc + 1) * 4096 + row * 64 + scol);
                vreg[p] = *(const uint4*)(Vbase + (size_t)row * SEQ + (kc + 1) * 64 + scol);
            }
        }

        // S^T tiles: C[key][q], key = ktile*32 + (reg&3)+8*(reg>>2)+4h, q = l31
        f32x16 s0, s1;
#pragma unroll
        for (int r = 0; r < 16; ++r) { s0[r] = 0.f; s1[r] = 0.f; }

        __builtin_amdgcn_s_setprio(1);
#pragma unroll
        for (int dt = 0; dt < 4; ++dt) {
            short8 k0 = *(const short8*)(&Ks[buf][l31 * 72 + dt * 16 + h * 8]);
            short8 k1 = *(const short8*)(&Ks[buf][(32 + l31) * 72 + dt * 16 + h * 8]);
            s0 = __builtin_amdgcn_mfma_f32_32x32x16_bf16(k0, qf[dt], s0, 0, 0, 0);
            s1 = __builtin_amdgcn_mfma_f32_32x32x16_bf16(k1, qf[dt], s1, 0, 0, 0);
        }
        __builtin_amdgcn_s_setprio(0);

#pragma unroll
        for (int r = 0; r < 16; ++r) {
            s0[r] = __builtin_amdgcn_exp2f(s0[r]);
            s1[r] = __builtin_amdgcn_exp2f(s1[r]);
        }

        // lane-local pack to PV A-frags; partner 4-groups via shfl_xor(32)
        short8 fr[4];
        {
            unsigned e0 = cvt_pk_bf16(s0[0],  s0[1]),  e1 = cvt_pk_bf16(s0[2],  s0[3]);
            unsigned e2 = cvt_pk_bf16(s0[4],  s0[5]),  e3 = cvt_pk_bf16(s0[6],  s0[7]);
            unsigned e4 = cvt_pk_bf16(s0[8],  s0[9]),  e5 = cvt_pk_bf16(s0[10], s0[11]);
            unsigned e6 = cvt_pk_bf16(s0[12], s0[13]), e7 = cvt_pk_bf16(s0[14], s0[15]);
            unsigned x0 = __shfl_xor(e0, 32), x1 = __shfl_xor(e1, 32);
            unsigned x2 = __shfl_xor(e2, 32), x3 = __shfl_xor(e3, 32);
            unsigned x4 = __shfl_xor(e4, 32), x5 = __shfl_xor(e5, 32);
            unsigned x6 = __shfl_xor(e6, 32), x7 = __shfl_xor(e7, 32);
            fr[0] = mk8(h ? x2 : e0, h ? x3 : e1, h ? e2 : x0, h ? e3 : x1);
            fr[1] = mk8(h ? x6 : e4, h ? x7 : e5, h ? e6 : x4, h ? e7 : x5);
        }
        {
            unsigned e0 = cvt_pk_bf16(s1[0],  s1[1]),  e1 = cvt_pk_bf16(s1[2],  s1[3]);
            unsigned e2 = cvt_pk_bf16(s1[4],  s1[5]),  e3 = cvt_pk_bf16(s1[6],  s1[7]);
            unsigned e4 = cvt_pk_bf16(s1[8],  s1[9]),  e5 = cvt_pk_bf16(s1[10], s1[11]);
            unsigned e6 = cvt_pk_bf16(s1[12], s1[13]), e7 = cvt_pk_bf16(s1[14], s1[15]);
            unsigned x0 = __shfl_xor(e0, 32), x1 = __shfl_xor(e1, 32);
            unsigned x2 = __shfl_xor(e2, 32), x3 = __shfl_xor(e3, 32);
            unsigned x4 = __shfl_xor(e4, 32), x5 = __shfl_xor(e5, 32);
            unsigned x6 = __shfl_xor(e6, 32), x7 = __shfl_xor(e7, 32);
            fr[2] = mk8(h ? x2 : e0, h ? x3 : e1, h ? e2 : x0, h ? e3 : x1);
            fr[3] = mk8(h ? x6 : e4, h ? x7 : e5, h ? e6 : x4, h ? e7 : x5);
        }

        // O += P*V ; l += P*ones (C rows align with O rows)
        __builtin_amdgcn_s_setprio(1);
#pragma unroll
        for (int c = 0; c < 4; ++c) {
            short8 bv0 = *(const short8*)(&Vs[buf][l31 * 72 + c * 16 + h * 8]);
            short8 bv1 = *(const short8*)(&Vs[buf][(32 + l31) * 72 + c * 16 + h * 8]);
            o0 = __builtin_amdgcn_mfma_f32_32x32x16_bf16(fr[c], bv0, o0, 0, 0, 0);
            o1 = __builtin_amdgcn_mfma_f32_32x32x16_bf16(fr[c], bv1, o1, 0, 0, 0);
            ls = __builtin_amdgcn_mfma_f32_32x32x16_bf16(fr[c], ones,  ls, 0, 0, 0);
        }
        __builtin_amdgcn_s_setprio(0);
    }

    float inv[16];
#pragma unroll
    for (int r = 0; r < 16; ++r) inv[r] = 1.0f / ls[r];
#pragma unroll
    for (int r = 0; r < 16; ++r) {
        int row = q0 + w * 32 + (r & 3) + 8 * (r >> 2) + 4 * h;
        size_t rb = hbase + (size_t)row * 64 + l31;
        AO[rb]      = (unsigned short)f2bfr(o0[r] * inv[r]);
        AO[rb + 32] = (unsigned short)f2bfr(o1[r] * inv[r]);
    }
}

// ---------------- output projection: out = AO @ Wob^T + bo ----------------
// LDS-free, barrier-free per-wave GEMM (Round-4 proven version, 32x64/wave).
__global__ __launch_bounds__(256) void outproj_kernel(
    const unsigned short* __restrict__ AO, const unsigned short* __restrict__ Wob,
    const float* __restrict__ bo, float* __restrict__ out) {
    const int t = threadIdx.x, w = t >> 6, lane = t & 63;
    const int l31 = lane & 31, h = lane >> 5;

    const int wid = blockIdx.x * 4 + w;   // 2048 waves
    const int mt  = wid >> 4;             // 0..127 : 32-row tile of out
    const int et  = wid & 15;             // 0..15  : 64-col tile of out
    const int m0  = mt * 32, e0 = et * 64;
    const int b   = m0 >> 11;             // batch (m0 % 32 == 0, no crossing)
    const int s   = (m0 & 2047) + l31;    // seq row for this lane

    const unsigned short* pA  = AO + ((size_t)(b * 16) * SEQ + s) * 64 + h * 8;
    const unsigned short* pB0 = Wob + (size_t)(e0 + l31) * EMB + h * 8;
    const unsigned short* pB1 = Wob + (size_t)(e0 + 32 + l31) * EMB + h * 8;

    f32x16 c0, c1;
#pragma unroll
    for (int r = 0; r < 16; ++r) { c0[r] = 0.f; c1[r] = 0.f; }

    for (int hh = 0; hh < 16; ++hh) {
#pragma unroll
        for (int k4 = 0; k4 < 4; ++k4) {
            short8 a  = *(const short8*)(pA + k4 * 16);
            short8 b0 = *(const short8*)(pB0 + hh * 64 + k4 * 16);
            short8 b1 = *(const short8*)(pB1 + hh * 64 + k4 * 16);
            c0 = __builtin_amdgcn_mfma_f32_32x32x16_bf16(a, b0, c0, 0, 0, 0);
            c1 = __builtin_amdgcn_mfma_f32_32x32x16_bf16(a, b1, c1, 0, 0, 0);
        }
        pA += (size_t)SEQ * 64;  // next head along k
    }

    const float bias0 = bo[e0 + l31];
    const float bias1 = bo[e0 + 32 + l31];
#pragma unroll
    for (int r = 0; r < 16; ++r) {
        int m = m0 + (r & 3) + 8 * (r >> 2) + 4 * h;
        out[(size_t)m * EMB + e0 + l31]      = c0[r] + bias0;
        out[(size_t)m * EMB + e0 + 32 + l31] = c1[r] + bias1;
    }
}

extern "C" void kernel_launch(void* const* d_in, const int* in_sizes, int n_in,
                              void* d_out, int out_size, void* d_ws, size_t ws_size,
                              hipStream_t stream) {
    const float* values  = (const float*)d_in[0];
    const float* keys    = (const float*)d_in[1];
    const float* queries = (const float*)d_in[2];
    const float* Wv = (const float*)d_in[3];
    const float* Wk = (const float*)d_in[4];
    const float* Wq = (const float*)d_in[5];
    const float* Wo = (const float*)d_in[6];
    const float* bo = (const float*)d_in[7];
    float* out = (float*)d_out;

    char* ws = (char*)d_ws;
    unsigned short* Qp  = (unsigned short*)(ws);                 // 8 MB (B,H,S,D) bf16
    unsigned short* Kp  = (unsigned short*)(ws + (8u  << 20));   // 8 MB (B,H,S,D) bf16
    unsigned short* Vt  = (unsigned short*)(ws + (16u << 20));   // 8 MB (B,H,D,S) bf16
    unsigned short* AO  = (unsigned short*)(ws + (24u << 20));   // 8 MB (B,H,S,D) bf16
    unsigned short* Wob = (unsigned short*)(ws + (32u << 20));   // 2 MB [e][k] bf16

    proj_kernel<<<dim3(SEQ / 64, BATCH * HEADS, 4), dim3(256), 0, stream>>>(
        values, keys, queries, Wv, Wk, Wq, Wo, Qp, Kp, Vt, Wob);
    attn_kernel<<<dim3((SEQ / 128) * BATCH * HEADS), dim3(256), 0, stream>>>(Qp, Kp, Vt, AO);
    outproj_kernel<<<dim3((EMB / 64) * ((BATCH * SEQ) / 32) / 4), dim3(256), 0, stream>>>(
        AO, Wob, bo, out);
}

// Round 11
// 229.226 us; speedup vs baseline: 1.0709x; 1.0062x over previous
//
#include <hip/hip_runtime.h>
#include <stdint.h>

#define HEADS 16
#define HD    64
#define SEQ   2048
#define BATCH 2
#define EMB   1024

using short8  = __attribute__((ext_vector_type(8))) short;
using float4v = __attribute__((ext_vector_type(4))) float;
using f32x16  = __attribute__((ext_vector_type(16))) float;

// round-half-up f32 -> bf16 (2 VALU ops); inputs never NaN/overflow here
__device__ __forceinline__ unsigned int f2bfr(float f) {
    return (__float_as_uint(f) + 0x8000u) >> 16;
}

// pack two f32 -> bf16x2 dword (RNE), single VOP3
__device__ __forceinline__ unsigned int cvt_pk_bf16(float lo, float hi) {
    unsigned int r;
    asm("v_cvt_pk_bf16_f32 %0, %1, %2" : "=v"(r) : "v"(lo), "v"(hi));
    return r;
}

// swap with lane^1 (quad_perm [1,0,3,2])
__device__ __forceinline__ unsigned int dpp_xor1(unsigned int x) {
    return (unsigned int)__builtin_amdgcn_update_dpp(0, (int)x, 0xB1, 0xF, 0xF, true);
}

__device__ __forceinline__ short8 mk8(unsigned int a, unsigned int b,
                                      unsigned int c, unsigned int d) {
    union { unsigned int u[4]; short8 s; } x;
    x.u[0] = a; x.u[1] = b; x.u[2] = c; x.u[3] = d;
    return x.s;
}

// ---------------- QKV projection (MFMA) + fused Wo conversion ----------------
// z=0: queries->Qp (B,H,S,D) [pre-scaled by 0.125*log2e via Wq]
// z=1: keys->Kp (B,H,S,D)    z=2: values->Vt (B,H,D,S)
// z=3: Wo fp32 -> bf16 (folded former cvt_wo_kernel)
__global__ __launch_bounds__(256) void proj_kernel(
    const float* __restrict__ Vx, const float* __restrict__ Kx, const float* __restrict__ Qx,
    const float* __restrict__ Wv, const float* __restrict__ Wk, const float* __restrict__ Wq,
    const float* __restrict__ Wo,
    unsigned short* __restrict__ Qp, unsigned short* __restrict__ Kp,
    unsigned short* __restrict__ Vt, unsigned short* __restrict__ Wob) {
    __shared__ __align__(16) unsigned short Ws[64 * 72];   // B-frag: Ws[e][d]
    __shared__ __align__(16) unsigned short xs[64 * 72];   // A-frag: xs[s][d]; reused for repack
    __shared__ __align__(16) unsigned short vt2[64 * 72];  // z==2 transpose buffer [e][s]

    const int t = threadIdx.x, w = t >> 6, lane = t & 63, cl = lane & 15, quad = lane >> 4;
    const int z  = blockIdx.z;

    if (z == 3) {  // Wo fp32 -> bf16 (block-uniform branch, no barriers touched)
        int cb = blockIdx.y * 32 + blockIdx.x;
        int i = (cb * 256 + t) * 4;
        float4 v = *(const float4*)(Wo + i);
        uint2 o;
        o.x = f2bfr(v.x) | (f2bfr(v.y) << 16);
        o.y = f2bfr(v.z) | (f2bfr(v.w) << 16);
        *(uint2*)(Wob + i) = o;
        return;
    }

    const int bh = blockIdx.y;
    const int b  = bh >> 4, h = bh & 15;
    const int s0 = blockIdx.x * 64;

    const float* x = (z == 0) ? Qx : (z == 1) ? Kx : Vx;
    const float* W = (z == 0) ? Wq : (z == 1) ? Wk : Wv;
    const float scale = (z == 0) ? 0.18033688011112044f : 1.0f;  // 0.125*log2(e)

#pragma unroll
    for (int rep = 0; rep < 4; ++rep) {
        int idx = rep * 1024 + t * 4;
        int e = idx >> 6, d0 = idx & 63;
        float4 w4 = *(const float4*)(W + idx);
        uint2 pk;
        pk.x = f2bfr(w4.x * scale) | (f2bfr(w4.y * scale) << 16);
        pk.y = f2bfr(w4.z * scale) | (f2bfr(w4.w * scale) << 16);
        *(uint2*)(&Ws[e * 72 + d0]) = pk;

        int s = e;
        float4 v4 = *(const float4*)(x + (size_t)(b * SEQ + s0 + s) * EMB + h * 64 + d0);
        uint2 px;
        px.x = f2bfr(v4.x) | (f2bfr(v4.y) << 16);
        px.y = f2bfr(v4.z) | (f2bfr(v4.w) << 16);
        *(uint2*)(&xs[s * 72 + d0]) = px;
    }
    __syncthreads();

    short8 a0 = *(const short8*)(&xs[(w * 16 + cl) * 72 + quad * 8]);
    short8 a1 = *(const short8*)(&xs[(w * 16 + cl) * 72 + 32 + quad * 8]);
    float4v c[4];
#pragma unroll
    for (int nt = 0; nt < 4; ++nt) c[nt] = (float4v){0.f, 0.f, 0.f, 0.f};
#pragma unroll
    for (int nt = 0; nt < 4; ++nt) {
        short8 b0 = *(const short8*)(&Ws[(nt * 16 + cl) * 72 + quad * 8]);
        c[nt] = __builtin_amdgcn_mfma_f32_16x16x32_bf16(a0, b0, c[nt], 0, 0, 0);
        short8 b1 = *(const short8*)(&Ws[(nt * 16 + cl) * 72 + 32 + quad * 8]);
        c[nt] = __builtin_amdgcn_mfma_f32_16x16x32_bf16(a1, b1, c[nt], 0, 0, 0);
    }

    if (z < 2) {
        // repack via DPP pair-pack (cols cl,cl^1 in adjacent lanes): 8 ds_write_b32
        const int even = ((lane & 1) == 0);
        const unsigned int psel = even ? 0x03020706u : 0x07060302u;
        const int evoff = even ? 0 : 16;  // odd lanes write nt{2,3} dword blocks
        unsigned int* Pw = (unsigned int*)xs;
#pragma unroll
        for (int r = 0; r < 4; ++r) {
            unsigned int rr[4], wd[4];
#pragma unroll
            for (int nt = 0; nt < 4; ++nt)
                rr[nt] = __float_as_uint(c[nt][r]) + 0x8000u;
#pragma unroll
            for (int nt = 0; nt < 4; ++nt) {
                unsigned int nb = dpp_xor1(rr[nt]);
                wd[nt] = __builtin_amdgcn_perm(rr[nt], nb, psel);
            }
            int dwbase = (w * 16 + quad * 4 + r) * 36 + evoff + (cl >> 1);
            Pw[dwbase]     = even ? wd[0] : wd[2];
            Pw[dwbase + 8] = even ? wd[1] : wd[3];
        }
        unsigned short* outp = (z == 0) ? Qp : Kp;
        int sl = w * 16 + (lane >> 2), c0 = (lane & 3) * 16;
        uint4 o0 = *(const uint4*)(&xs[sl * 72 + c0]);
        uint4 o1 = *(const uint4*)(&xs[sl * 72 + c0 + 8]);
        size_t base = ((size_t)bh * SEQ + s0 + sl) * 64 + c0;
        *(uint4*)(outp + base)     = o0;
        *(uint4*)(outp + base + 8) = o1;
    } else {
        // transpose repack: lane holds 4 consecutive cols (r) per nt-row
#pragma unroll
        for (int nt = 0; nt < 4; ++nt) {
            uint2 pk;
            pk.x = f2bfr(c[nt][0]) | (f2bfr(c[nt][1]) << 16);
            pk.y = f2bfr(c[nt][2]) | (f2bfr(c[nt][3]) << 16);
            *(uint2*)(&vt2[(nt * 16 + cl) * 72 + w * 16 + quad * 4]) = pk;
        }
        __syncthreads();
        int e = t >> 2, sc0 = (t & 3) * 16;
        uint4 o0 = *(const uint4*)(&vt2[e * 72 + sc0]);
        uint4 o1 = *(const uint4*)(&vt2[e * 72 + sc0 + 8]);
        size_t base = ((size_t)bh * 64 + e) * SEQ + s0 + sc0;
        *(uint4*)(Vt + base)     = o0;
        *(uint4*)(Vt + base + 8) = o1;
    }
}

// ---------------- flash attention, swapped-QK 32x32 in-register softmax ----------------
// (verbatim Round-4 kernel: proven correct at 88.5us)
__global__ __launch_bounds__(256) void attn_kernel(
    const unsigned short* __restrict__ Qp, const unsigned short* __restrict__ Kp,
    const unsigned short* __restrict__ Vt, unsigned short* __restrict__ AO) {
    __shared__ __align__(16) unsigned short Ks[2][64 * 72];   // [key][d]
    __shared__ __align__(16) unsigned short Vs[2][64 * 72];   // [d][key]

    const int t = threadIdx.x;
    const int w = t >> 6, lane = t & 63;
    const int l31 = lane & 31, h = lane >> 5;

    // XCD-aware swizzle: lid%8 -> XCD; give each XCD 4 heads (K+V = 2MB fits L2)
    const int lid = blockIdx.x;
    const int bh  = ((lid & 7) << 2) | ((lid >> 3) & 3);
    const int q0  = (lid >> 5) * 128;

    const size_t hbase = (size_t)bh * SEQ * 64;
    const unsigned short* Kbase = Kp + hbase;
    const unsigned short* Vbase = Vt + hbase;

    // Q B-frags: lane holds q = q0 + w*32 + l31, d = dt*16 + h*8 + j
    short8 qf[4];
    {
        const unsigned short* qr = Qp + hbase + (size_t)(q0 + w * 32 + l31) * 64 + h * 8;
#pragma unroll
        for (int dt = 0; dt < 4; ++dt) qf[dt] = *(const short8*)(qr + dt * 16);
    }

    short8 ones;
#pragma unroll
    for (int i = 0; i < 8; ++i) ones[i] = (short)0x3F80;  // bf16 1.0

    f32x16 o0, o1, ls;
#pragma unroll
    for (int r = 0; r < 16; ++r) { o0[r] = 0.f; o1[r] = 0.f; ls[r] = 0.f; }

    const int srow = t >> 3;       // 0..31
    const int scol = (t & 7) * 8;  // 0..56

    uint4 kreg[2], vreg[2];
#pragma unroll
    for (int p = 0; p < 2; ++p) {
        int row = srow + p * 32;
        kreg[p] = *(const uint4*)(Kbase + row * 64 + scol);
        vreg[p] = *(const uint4*)(Vbase + (size_t)row * SEQ + scol);
    }

    for (int kc = 0; kc < SEQ / 64; ++kc) {
        const int buf = kc & 1;
#pragma unroll
        for (int p = 0; p < 2; ++p) {
            int row = srow + p * 32;
            *(uint4*)(&Ks[buf][row * 72 + scol]) = kreg[p];
            *(uint4*)(&Vs[buf][row * 72 + scol]) = vreg[p];
        }
        __syncthreads();
        if (kc + 1 < SEQ / 64) {
#pragma unroll
            for (int p = 0; p < 2; ++p) {
                int row = srow + p * 32;
                kreg[p] = *(const uint4*)(Kbase + (size_t)(kc + 1) * 4096 + row * 64 + scol);
                vreg[p] = *(const uint4*)(Vbase + (size_t)row * SEQ + (kc + 1) * 64 + scol);
            }
        }

        // S^T tiles: C[key][q], key = ktile*32 + (reg&3)+8*(reg>>2)+4h, q = l31
        f32x16 s0, s1;
#pragma unroll
        for (int r = 0; r < 16; ++r) { s0[r] = 0.f; s1[r] = 0.f; }

        __builtin_amdgcn_s_setprio(1);
#pragma unroll
        for (int dt = 0; dt < 4; ++dt) {
            short8 k0 = *(const short8*)(&Ks[buf][l31 * 72 + dt * 16 + h * 8]);
            short8 k1 = *(const short8*)(&Ks[buf][(32 + l31) * 72 + dt * 16 + h * 8]);
            s0 = __builtin_amdgcn_mfma_f32_32x32x16_bf16(k0, qf[dt], s0, 0, 0, 0);
            s1 = __builtin_amdgcn_mfma_f32_32x32x16_bf16(k1, qf[dt], s1, 0, 0, 0);
        }
        __builtin_amdgcn_s_setprio(0);

#pragma unroll
        for (int r = 0; r < 16; ++r) {
            s0[r] = __builtin_amdgcn_exp2f(s0[r]);
            s1[r] = __builtin_amdgcn_exp2f(s1[r]);
        }

        // lane-local pack to PV A-frags; partner 4-groups via shfl_xor(32)
        short8 fr[4];
        {
            unsigned e0 = cvt_pk_bf16(s0[0],  s0[1]),  e1 = cvt_pk_bf16(s0[2],  s0[3]);
            unsigned e2 = cvt_pk_bf16(s0[4],  s0[5]),  e3 = cvt_pk_bf16(s0[6],  s0[7]);
            unsigned e4 = cvt_pk_bf16(s0[8],  s0[9]),  e5 = cvt_pk_bf16(s0[10], s0[11]);
            unsigned e6 = cvt_pk_bf16(s0[12], s0[13]), e7 = cvt_pk_bf16(s0[14], s0[15]);
            unsigned x0 = __shfl_xor(e0, 32), x1 = __shfl_xor(e1, 32);
            unsigned x2 = __shfl_xor(e2, 32), x3 = __shfl_xor(e3, 32);
            unsigned x4 = __shfl_xor(e4, 32), x5 = __shfl_xor(e5, 32);
            unsigned x6 = __shfl_xor(e6, 32), x7 = __shfl_xor(e7, 32);
            fr[0] = mk8(h ? x2 : e0, h ? x3 : e1, h ? e2 : x0, h ? e3 : x1);
            fr[1] = mk8(h ? x6 : e4, h ? x7 : e5, h ? e6 : x4, h ? e7 : x5);
        }
        {
            unsigned e0 = cvt_pk_bf16(s1[0],  s1[1]),  e1 = cvt_pk_bf16(s1[2],  s1[3]);
            unsigned e2 = cvt_pk_bf16(s1[4],  s1[5]),  e3 = cvt_pk_bf16(s1[6],  s1[7]);
            unsigned e4 = cvt_pk_bf16(s1[8],  s1[9]),  e5 = cvt_pk_bf16(s1[10], s1[11]);
            unsigned e6 = cvt_pk_bf16(s1[12], s1[13]), e7 = cvt_pk_bf16(s1[14], s1[15]);
            unsigned x0 = __shfl_xor(e0, 32), x1 = __shfl_xor(e1, 32);
            unsigned x2 = __shfl_xor(e2, 32), x3 = __shfl_xor(e3, 32);
            unsigned x4 = __shfl_xor(e4, 32), x5 = __shfl_xor(e5, 32);
            unsigned x6 = __shfl_xor(e6, 32), x7 = __shfl_xor(e7, 32);
            fr[2] = mk8(h ? x2 : e0, h ? x3 : e1, h ? e2 : x0, h ? e3 : x1);
            fr[3] = mk8(h ? x6 : e4, h ? x7 : e5, h ? e6 : x4, h ? e7 : x5);
        }

        // O += P*V ; l += P*ones (C rows align with O rows)
        __builtin_amdgcn_s_setprio(1);
#pragma unroll
        for (int c = 0; c < 4; ++c) {
            short8 bv0 = *(const short8*)(&Vs[buf][l31 * 72 + c * 16 + h * 8]);
            short8 bv1 = *(const short8*)(&Vs[buf][(32 + l31) * 72 + c * 16 + h * 8]);
            o0 = __builtin_amdgcn_mfma_f32_32x32x16_bf16(fr[c], bv0, o0, 0, 0, 0);
            o1 = __builtin_amdgcn_mfma_f32_32x32x16_bf16(fr[c], bv1, o1, 0, 0, 0);
            ls = __builtin_amdgcn_mfma_f32_32x32x16_bf16(fr[c], ones,  ls, 0, 0, 0);
        }
        __builtin_amdgcn_s_setprio(0);
    }

    float inv[16];
#pragma unroll
    for (int r = 0; r < 16; ++r) inv[r] = 1.0f / ls[r];
#pragma unroll
    for (int r = 0; r < 16; ++r) {
        int row = q0 + w * 32 + (r & 3) + 8 * (r >> 2) + 4 * h;
        size_t rb = hbase + (size_t)row * 64 + l31;
        AO[rb]      = (unsigned short)f2bfr(o0[r] * inv[r]);
        AO[rb + 32] = (unsigned short)f2bfr(o1[r] * inv[r]);
    }
}

// ---------------- output projection: out = AO @ Wob^T + bo ----------------
// R10's barrier-free per-wave GEMM + explicit depth-1 software pipeline:
// hh+1's 12 fragments load into _n regs BEFORE hh's MFMAs issue; rotation via
// register copies in a fully-unrolled loop (constant indices -> SSA renames).
// Per-iteration stall drops from lat_L2+MFMA to max(lat_L2, MFMA).
__global__ __launch_bounds__(256) void outproj_kernel(
    const unsigned short* __restrict__ AO, const unsigned short* __restrict__ Wob,
    const float* __restrict__ bo, float* __restrict__ out) {
    const int t = threadIdx.x, w = t >> 6, lane = t & 63;
    const int l31 = lane & 31, h = lane >> 5;

    const int wid = blockIdx.x * 4 + w;   // 2048 waves
    const int mt  = wid >> 4;             // 0..127 : 32-row tile of out
    const int et  = wid & 15;             // 0..15  : 64-col tile of out
    const int m0  = mt * 32, e0 = et * 64;
    const int b   = m0 >> 11;             // batch (m0 % 32 == 0, no crossing)
    const int s   = (m0 & 2047) + l31;    // seq row for this lane

    const unsigned short* pA  = AO + ((size_t)(b * 16) * SEQ + s) * 64 + h * 8;
    const unsigned short* pB0 = Wob + (size_t)(e0 + l31) * EMB + h * 8;
    const unsigned short* pB1 = Wob + (size_t)(e0 + 32 + l31) * EMB + h * 8;

    f32x16 c0, c1;
#pragma unroll
    for (int r = 0; r < 16; ++r) { c0[r] = 0.f; c1[r] = 0.f; }

    short8 a_c[4], b0_c[4], b1_c[4];
#pragma unroll
    for (int k4 = 0; k4 < 4; ++k4) {
        a_c[k4]  = *(const short8*)(pA + k4 * 16);
        b0_c[k4] = *(const short8*)(pB0 + k4 * 16);
        b1_c[k4] = *(const short8*)(pB1 + k4 * 16);
    }

#pragma unroll
    for (int hh = 0; hh < 16; ++hh) {
        short8 a_n[4], b0_n[4], b1_n[4];
        if (hh + 1 < 16) {
            const unsigned short* pAn = pA + (size_t)(hh + 1) * SEQ * 64;
#pragma unroll
            for (int k4 = 0; k4 < 4; ++k4) {
                a_n[k4]  = *(const short8*)(pAn + k4 * 16);
                b0_n[k4] = *(const short8*)(pB0 + (hh + 1) * 64 + k4 * 16);
                b1_n[k4] = *(const short8*)(pB1 + (hh + 1) * 64 + k4 * 16);
            }
        }
#pragma unroll
        for (int k4 = 0; k4 < 4; ++k4) {
            c0 = __builtin_amdgcn_mfma_f32_32x32x16_bf16(a_c[k4], b0_c[k4], c0, 0, 0, 0);
            c1 = __builtin_amdgcn_mfma_f32_32x32x16_bf16(a_c[k4], b1_c[k4], c1, 0, 0, 0);
        }
        if (hh + 1 < 16) {
#pragma unroll
            for (int k4 = 0; k4 < 4; ++k4) {
                a_c[k4] = a_n[k4]; b0_c[k4] = b0_n[k4]; b1_c[k4] = b1_n[k4];
            }
        }
    }

    const float bias0 = bo[e0 + l31];
    const float bias1 = bo[e0 + 32 + l31];
#pragma unroll
    for (int r = 0; r < 16; ++r) {
        int m = m0 + (r & 3) + 8 * (r >> 2) + 4 * h;
        out[(size_t)m * EMB + e0 + l31]      = c0[r] + bias0;
        out[(size_t)m * EMB + e0 + 32 + l31] = c1[r] + bias1;
    }
}

extern "C" void kernel_launch(void* const* d_in, const int* in_sizes, int n_in,
                              void* d_out, int out_size, void* d_ws, size_t ws_size,
                              hipStream_t stream) {
    const float* values  = (const float*)d_in[0];
    const float* keys    = (const float*)d_in[1];
    const float* queries = (const float*)d_in[2];
    const float* Wv = (const float*)d_in[3];
    const float* Wk = (const float*)d_in[4];
    const float* Wq = (const float*)d_in[5];
    const float* Wo = (const float*)d_in[6];
    const float* bo = (const float*)d_in[7];
    float* out = (float*)d_out;

    char* ws = (char*)d_ws;
    unsigned short* Qp  = (unsigned short*)(ws);                 // 8 MB (B,H,S,D) bf16
    unsigned short* Kp  = (unsigned short*)(ws + (8u  << 20));   // 8 MB (B,H,S,D) bf16
    unsigned short* Vt  = (unsigned short*)(ws + (16u << 20));   // 8 MB (B,H,D,S) bf16
    unsigned short* AO  = (unsigned short*)(ws + (24u << 20));   // 8 MB (B,H,S,D) bf16
    unsigned short* Wob = (unsigned short*)(ws + (32u << 20));   // 2 MB [e][k] bf16

    proj_kernel<<<dim3(SEQ / 64, BATCH * HEADS, 4), dim3(256), 0, stream>>>(
        values, keys, queries, Wv, Wk, Wq, Wo, Qp, Kp, Vt, Wob);
    attn_kernel<<<dim3((SEQ / 128) * BATCH * HEADS), dim3(256), 0, stream>>>(Qp, Kp, Vt, AO);
    outproj_kernel<<<dim3((EMB / 64) * ((BATCH * SEQ) / 32) / 4), dim3(256), 0, stream>>>(
        AO, Wob, bo, out);
}